// Round 7
// baseline (131.092 us; speedup 1.0000x reference)
//
#include <hip/hip_runtime.h>
#include <cstdint>
#include <cstddef>

#define BATCH 8
#define SEQ 1024
#define DIM 768
#define EPS_K 1e-7f

typedef __bf16 bf16x8 __attribute__((ext_vector_type(8)));
typedef float f32x4 __attribute__((ext_vector_type(4)));
typedef uint16_t u16x8 __attribute__((ext_vector_type(8)));

#define MFMA16(a, b, c) __builtin_amdgcn_mfma_f32_16x16x32_bf16((a), (b), (c), 0, 0, 0)

__device__ __forceinline__ uint16_t f2bf(float f) {
  union { float f; uint32_t u; } v; v.f = f;
  uint32_t u = v.u;
  u += 0x7FFFu + ((u >> 16) & 1u);   // RNE to bf16
  return (uint16_t)(u >> 16);
}

__device__ __forceinline__ void gload16(const void* g, void* l) {
  __builtin_amdgcn_global_load_lds(
      (const __attribute__((address_space(1))) uint32_t*)g,
      (__attribute__((address_space(3))) uint32_t*)l, 16, 0, 0);
}

// ---------------------------------------------------------------------------
// Kernel 1: fp32 -> bf16 convert: ab[b][s][d] row-major, at[b][d][s] transposed
// ---------------------------------------------------------------------------
__global__ __launch_bounds__(256) void convert_kernel(const float* __restrict__ A,
                                                      uint16_t* __restrict__ ab,
                                                      uint16_t* __restrict__ at) {
  const int b  = blockIdx.z;
  const int s0 = blockIdx.y * 64;
  const int d0 = blockIdx.x * 64;
  __shared__ uint16_t tl[64][80];
  const int tid = threadIdx.x;
#pragma unroll
  for (int i = 0; i < 2; ++i) {
    const int sl = (tid >> 3) + i * 32;
    const int ch = tid & 7;
    const float* src = A + ((size_t)b * SEQ + s0 + sl) * DIM + d0 + ch * 8;
    float4 f0 = *(const float4*)src;
    float4 f1 = *(const float4*)(src + 4);
    u16x8 h;
    h[0] = f2bf(f0.x); h[1] = f2bf(f0.y); h[2] = f2bf(f0.z); h[3] = f2bf(f0.w);
    h[4] = f2bf(f1.x); h[5] = f2bf(f1.y); h[6] = f2bf(f1.z); h[7] = f2bf(f1.w);
    *(u16x8*)&ab[((size_t)b * SEQ + s0 + sl) * DIM + d0 + ch * 8] = h;
    *(u16x8*)&tl[sl][ch * 8] = h;
  }
  __syncthreads();
  const int dl = tid >> 2;
#pragma unroll
  for (int i = 0; i < 2; ++i) {
    const int sc = (tid & 3) + i * 4;
    u16x8 h;
#pragma unroll
    for (int e = 0; e < 8; ++e) h[e] = tl[sc * 8 + e][dl];
    *(u16x8*)&at[((size_t)b * DIM + d0 + dl) * SEQ + s0 + sc * 8] = h;
  }
}

// ---------------------------------------------------------------------------
// Shared GEMM geometry (kernels 2 & 3): BM=128, BN=64, BK=32, 4 waves (2Mx2N),
// per-wave 64x32 out (4x2 frags of 16x16x32). LDS [2][128|64][32] bf16,
// linear layout (R3-proven). 2-phase: stage(next) at top, one barrier/iter.
// Grids: 1024 / 768 blocks -> 3-4 blocks/CU, 12-16 waves/CU (the occupancy
// regime the m97-class kernels run in; R3-R6 were all stuck at 8 waves/CU).
// ---------------------------------------------------------------------------

// Kernel 2: P[b][q][t] = m_q*m_t*exp(ab[q]·ab[t])  (bf16)
__global__ __launch_bounds__(256) void scores_kernel(const uint16_t* __restrict__ ab,
                                                     const int* __restrict__ mask,
                                                     uint16_t* __restrict__ P) {
  const int b    = blockIdx.x & 7;
  const int tile = blockIdx.x >> 3;          // 0..127
  const int s0   = (tile >> 4) * 128;
  const int t0   = (tile & 15) * 64;

  const int tid  = threadIdx.x;
  const int lane = tid & 63;
  const int wid  = tid >> 6;
  const int wr   = wid >> 1;                 // 0..1 (M)
  const int wc   = wid & 1;                  // 0..1 (N)

  __shared__ __align__(16) uint16_t lQ[2][128 * 32];
  __shared__ __align__(16) uint16_t lK[2][64 * 32];
  __shared__ float mrow[128];
  __shared__ float mcol[64];

  if (tid < 128)                  mrow[tid]       = (float)mask[b * SEQ + s0 + tid];
  else if (tid < 192)             mcol[tid - 128] = (float)mask[b * SEQ + t0 + (tid - 128)];

  const uint16_t* gQ = ab + ((size_t)b * SEQ + s0) * DIM;
  const uint16_t* gK = ab + ((size_t)b * SEQ + t0) * DIM;

  // staging: A rows t>>2 and +64 (2 loads), B row t>>2 (1 load); chunk t&3
  const int strow = tid >> 2;
  const int sch   = (tid & 3) * 8;
  const int sdst  = tid * 8;
#define STG(buf, k0)                                                           \
  { gload16(gQ + (size_t)strow * DIM + (k0) + sch, &lQ[buf][sdst]);            \
    gload16(gQ + (size_t)(strow + 64) * DIM + (k0) + sch, &lQ[buf][sdst + 2048]); \
    gload16(gK + (size_t)strow * DIM + (k0) + sch, &lK[buf][sdst]); }

  f32x4 acc[4][2];
#pragma unroll
  for (int m = 0; m < 4; ++m)
#pragma unroll
    for (int n = 0; n < 2; ++n) acc[m][n] = f32x4{0.f, 0.f, 0.f, 0.f};

  const int rQ  = wr * 64 + (lane & 15);
  const int rK  = wc * 32 + (lane & 15);
  const int kch = (lane >> 4) * 8;

  STG(0, 0);
  __syncthreads();

  const int NT = DIM / 32;                   // 24
  int cur = 0;
  for (int t = 0; t < NT; ++t) {
    if (t + 1 < NT) STG(cur ^ 1, (t + 1) * 32);

    bf16x8 qf[4], kf[2];
#pragma unroll
    for (int m = 0; m < 4; ++m) qf[m] = *(const bf16x8*)&lQ[cur][(rQ + m * 16) * 32 + kch];
#pragma unroll
    for (int n = 0; n < 2; ++n) kf[n] = *(const bf16x8*)&lK[cur][(rK + n * 16) * 32 + kch];
#pragma unroll
    for (int m = 0; m < 4; ++m)
#pragma unroll
      for (int n = 0; n < 2; ++n)
        acc[m][n] = MFMA16(qf[m], kf[n], acc[m][n]);

    __syncthreads();
    cur ^= 1;
  }
#undef STG

  // Epilogue: e = exp(S)*m_q*m_t, bf16 store.
  uint16_t* Pb = P + (size_t)b * SEQ * SEQ;
#pragma unroll
  for (int m = 0; m < 4; ++m) {
    const int qb = wr * 64 + m * 16 + (lane >> 4) * 4;
#pragma unroll
    for (int n = 0; n < 2; ++n) {
      const int tl = wc * 32 + n * 16 + (lane & 15);
      const float mc = mcol[tl];
#pragma unroll
      for (int j = 0; j < 4; ++j) {
        float e = __expf(acc[m][n][j]) * mrow[qb + j] * mc;
        Pb[(size_t)(s0 + qb + j) * SEQ + t0 + tl] = f2bf(e);
      }
    }
  }
}

// Kernel 3: out[b][q][d] = sum_t P[q][t]*at[d][t] / (den_q+eps)
// den via ones-B MFMA (C-row map matches the rows this lane writes).
__global__ __launch_bounds__(256) void out_kernel(const uint16_t* __restrict__ P,
                                                  const uint16_t* __restrict__ at,
                                                  float* __restrict__ out) {
  const int b    = blockIdx.x & 7;
  const int tile = blockIdx.x >> 3;          // 0..95
  const int q0   = (tile / 12) * 128;
  const int d0   = (tile % 12) * 64;

  const int tid  = threadIdx.x;
  const int lane = tid & 63;
  const int wid  = tid >> 6;
  const int wr   = wid >> 1;
  const int wc   = wid & 1;

  __shared__ __align__(16) uint16_t lP[2][128 * 32];
  __shared__ __align__(16) uint16_t lV[2][64 * 32];

  const uint16_t* gP = P  + ((size_t)b * SEQ + q0) * SEQ;
  const uint16_t* gV = at + ((size_t)b * DIM + d0) * SEQ;

  const int strow = tid >> 2;
  const int sch   = (tid & 3) * 8;
  const int sdst  = tid * 8;
#define STG(buf, k0)                                                           \
  { gload16(gP + (size_t)strow * SEQ + (k0) + sch, &lP[buf][sdst]);            \
    gload16(gP + (size_t)(strow + 64) * SEQ + (k0) + sch, &lP[buf][sdst + 2048]); \
    gload16(gV + (size_t)strow * SEQ + (k0) + sch, &lV[buf][sdst]); }

  f32x4 acc[4][2];
  f32x4 accd[4];
#pragma unroll
  for (int m = 0; m < 4; ++m) {
    accd[m] = f32x4{0.f, 0.f, 0.f, 0.f};
#pragma unroll
    for (int n = 0; n < 2; ++n) acc[m][n] = f32x4{0.f, 0.f, 0.f, 0.f};
  }
  bf16x8 ones;
#pragma unroll
  for (int i = 0; i < 8; ++i) ones[i] = (__bf16)1.0f;

  const int rP  = wr * 64 + (lane & 15);
  const int rV  = wc * 32 + (lane & 15);
  const int kch = (lane >> 4) * 8;

  STG(0, 0);
  __syncthreads();

  const int NT = SEQ / 32;                   // 32
  int cur = 0;
  for (int t = 0; t < NT; ++t) {
    if (t + 1 < NT) STG(cur ^ 1, (t + 1) * 32);

    bf16x8 pf[4], vf[2];
#pragma unroll
    for (int m = 0; m < 4; ++m) pf[m] = *(const bf16x8*)&lP[cur][(rP + m * 16) * 32 + kch];
#pragma unroll
    for (int n = 0; n < 2; ++n) vf[n] = *(const bf16x8*)&lV[cur][(rV + n * 16) * 32 + kch];
#pragma unroll
    for (int m = 0; m < 4; ++m) {
#pragma unroll
      for (int n = 0; n < 2; ++n)
        acc[m][n] = MFMA16(pf[m], vf[n], acc[m][n]);
      accd[m] = MFMA16(pf[m], ones, accd[m]);
    }

    __syncthreads();
    cur ^= 1;
  }
#undef STG

  float* ob = out + (size_t)b * SEQ * DIM;
#pragma unroll
  for (int m = 0; m < 4; ++m) {
#pragma unroll
    for (int j = 0; j < 4; ++j) {
      const int q  = q0 + wr * 64 + m * 16 + (lane >> 4) * 4 + j;
      const float sc = 1.0f / (accd[m][j] + EPS_K);
#pragma unroll
      for (int n = 0; n < 2; ++n) {
        const int d = d0 + wc * 32 + n * 16 + (lane & 15);
        ob[(size_t)q * DIM + d] = acc[m][n][j] * sc;
      }
    }
  }
}

// ---------------------------------------------------------------------------
extern "C" void kernel_launch(void* const* d_in, const int* in_sizes, int n_in,
                              void* d_out, int out_size, void* d_ws, size_t ws_size,
                              hipStream_t stream) {
  (void)in_sizes; (void)n_in; (void)out_size; (void)ws_size;
  const float* A    = (const float*)d_in[0];
  const int*   mask = (const int*)d_in[1];
  float*       out  = (float*)d_out;

  char* ws = (char*)d_ws;
  const size_t NB_AB = (size_t)BATCH * SEQ * DIM * 2;
  const size_t NB_AT = NB_AB;
  uint16_t* ab = (uint16_t*)(ws);
  uint16_t* at = (uint16_t*)(ws + NB_AB);
  uint16_t* P  = (uint16_t*)(ws + NB_AB + NB_AT);

  convert_kernel<<<dim3(DIM / 64, SEQ / 64, BATCH), dim3(256), 0, stream>>>(A, ab, at);
  scores_kernel<<<dim3(128 * BATCH), dim3(256), 0, stream>>>(ab, mask, P);
  out_kernel<<<dim3(96 * BATCH), dim3(256), 0, stream>>>(P, at, out);
}